// Round 5
// baseline (104.328 us; speedup 1.0000x reference)
//
#include <hip/hip_runtime.h>

// Problem constants
#define NB   8192
#define ND   256
#define NH1  50
#define NH2  32
#define NH3  18
#define RPB  16              // rows per block
#define NBLK (NB / RPB)      // 512 blocks
#define W1TS 260             // W1T LDS row stride (dwords), %4==0 for b128 align
#define WSS  40              // per-block ws slot stride (floats)

// ws layout: ws[b*WSS + c], c: [0..17] ysum part, [18..35] colsum(W_user) part,
//            [36] sum(log_denom) part. No atomics, no zero-init needed.

__device__ __forceinline__ float sigmoidf_fast(float v) {
    return 1.0f / (1.0f + __expf(-v));
}

// Cross-lane add via DPP (VALU pipe — NOT ds_bpermute/LDS pipe).
template <int CTRL, int RMASK>
__device__ __forceinline__ float dpp_add(float v) {
    int d = __builtin_amdgcn_update_dpp(0, __float_as_int(v), CTRL, RMASK, 0xF, true);
    return v + __int_as_float(d);
}

__global__ __launch_bounds__(256) void fused_main(
    const float* __restrict__ x, const float* __restrict__ y,
    const float* __restrict__ W1, const float* __restrict__ b1,
    const float* __restrict__ W2, const float* __restrict__ b2,
    const float* __restrict__ W3, const float* __restrict__ b3,
    float* __restrict__ out, float* __restrict__ ws)
{
    __shared__ float w1t[NH1 * W1TS];      // 52000 B; DEAD after layer 1 -> overlaid
    __shared__ float w2l[NH1 * NH2];       // 6400 B
    __shared__ float w3l[NH2 * NH3];       // 2304 B
    __shared__ float h1l[NH1][RPB];        // [j][row] sigmoided h1, 3200 B
    // total static: 63904 B < 64 KB. h2l/wul overlay w1t after the layer-1 barrier.
    float (*h2l)[NH2 + 2] = (float (*)[NH2 + 2])(w1t);          // 16*34 dwords
    float (*wul)[NH3 + 1] = (float (*)[NH3 + 1])(w1t + 600);    // 16*19 dwords, disjoint

    const int t   = threadIdx.x;
    const int ksl = t & 31;          // layer-1 k-slice (8 dwords of 256)
    const int rp  = t >> 5;          // layer-1 row-pair 0..7
    const int c16 = t & 15;          // layer-2/3 column slot
    const int row = t >> 4;          // layer-2/3 local row
    const int rbase = blockIdx.x * RPB;

    // ---- early x loads: 2 rows x 8 dwords, stays in flight over staging ----
    const float* xr = x + (size_t)(rbase + rp * 2) * ND + ksl * 8;
    const float4 xa0 = *reinterpret_cast<const float4*>(xr);
    const float4 xa1 = *reinterpret_cast<const float4*>(xr + 4);
    const float4 xb0 = *reinterpret_cast<const float4*>(xr + ND);
    const float4 xb1 = *reinterpret_cast<const float4*>(xr + ND + 4);

    // ---- stage weights into LDS (W1 transposed [j][k]) ----
    for (int e = t; e < ND * NH1; e += 256) {
        int k = e / NH1;
        int j = e - k * NH1;
        w1t[j * W1TS + k] = W1[e];
    }
    for (int e = t; e < NH1 * NH2; e += 256) w2l[e] = W2[e];
    for (int e = t; e < NH2 * NH3; e += 256) w3l[e] = W3[e];
    __syncthreads();

    // ---- layer 1: per j, each lane does 8k x 2 rows, then 5-stage DPP reduce
    //      over its 32-lane half; lanes 16/48 write sigmoided sums to h1l ----
    {
        const float* wb = &w1t[ksl * 8];
#pragma unroll 2
        for (int j = 0; j < NH1; ++j) {
            const float4 w0 = *reinterpret_cast<const float4*>(wb + j * W1TS);
            const float4 w1v = *reinterpret_cast<const float4*>(wb + j * W1TS + 4);
            float s0 = xa0.x * w0.x;
            s0 = fmaf(xa0.y, w0.y, s0);
            s0 = fmaf(xa0.z, w0.z, s0);
            s0 = fmaf(xa0.w, w0.w, s0);
            s0 = fmaf(xa1.x, w1v.x, s0);
            s0 = fmaf(xa1.y, w1v.y, s0);
            s0 = fmaf(xa1.z, w1v.z, s0);
            s0 = fmaf(xa1.w, w1v.w, s0);
            float s1 = xb0.x * w0.x;
            s1 = fmaf(xb0.y, w0.y, s1);
            s1 = fmaf(xb0.z, w0.z, s1);
            s1 = fmaf(xb0.w, w0.w, s1);
            s1 = fmaf(xb1.x, w1v.x, s1);
            s1 = fmaf(xb1.y, w1v.y, s1);
            s1 = fmaf(xb1.z, w1v.z, s1);
            s1 = fmaf(xb1.w, w1v.w, s1);
            // butterfly within each row-of-16 (xor1,2,4,8) — all lanes get 16-sum
            s0 = dpp_add<0xB1, 0xF>(s0);  s1 = dpp_add<0xB1, 0xF>(s1);  // quad_perm(1,0,3,2)
            s0 = dpp_add<0x4E, 0xF>(s0);  s1 = dpp_add<0x4E, 0xF>(s1);  // quad_perm(2,3,0,1)
            s0 = dpp_add<0x141, 0xF>(s0); s1 = dpp_add<0x141, 0xF>(s1); // row_half_mirror
            s0 = dpp_add<0x140, 0xF>(s0); s1 = dpp_add<0x140, 0xF>(s1); // row_mirror
            // combine row pairs: rows 1,3 += lane15/47 value (full 16-sum of rows 0,2)
            s0 = dpp_add<0x142, 0xA>(s0); s1 = dpp_add<0x142, 0xA>(s1); // row_bcast15
            if ((t & 31) == 16) {          // lanes 16,48: hold full 32-lane sums
                const float bj = b1[j];
                *reinterpret_cast<float2*>(&h1l[j][rp * 2]) =
                    make_float2(sigmoidf_fast(s0 + bj), sigmoidf_fast(s1 + bj));
            }
        }
    }
    __syncthreads();   // h1l ready; w1t dead -> overlay region valid

    // ---- layer 2: each lane computes 2 of 32 cols for its row ----
    {
        const float2 bb = *reinterpret_cast<const float2*>(b2 + 2 * c16);
        float h2a = bb.x, h2b = bb.y;
#pragma unroll
        for (int j = 0; j < NH1; ++j) {
            const float h = h1l[j][row];                 // 16-way broadcast, free
            const float2 w = *reinterpret_cast<const float2*>(&w2l[j * NH2 + 2 * c16]);
            h2a = fmaf(h, w.x, h2a);
            h2b = fmaf(h, w.y, h2b);
        }
        *reinterpret_cast<float2*>(&h2l[row][2 * c16]) =
            make_float2(sigmoidf_fast(h2a), sigmoidf_fast(h2b));
    }
    __syncthreads();

    // ---- layer 3: lane computes col c16 (and 16+c16 for c16<2) ----
    {
        float a0 = b3[c16];
        float a1 = (c16 < 2) ? b3[16 + c16] : 0.0f;
#pragma unroll
        for (int j = 0; j < NH2; ++j) {
            const float h = h2l[row][j];
            a0 = fmaf(h, w3l[j * NH3 + c16], a0);
            if (c16 < 2) a1 = fmaf(h, w3l[j * NH3 + 16 + c16], a1);
        }
        const int grow = rbase + row;
        wul[row][c16] = a0;
        out[(size_t)grow * NH3 + c16] = a0;
        if (c16 < 2) {
            wul[row][16 + c16] = a1;
            out[(size_t)grow * NH3 + 16 + c16] = a1;
        }
    }
    __syncthreads();

    // ---- epilogue on wave 0: factorized LSE + block reductions, no atomics ----
    if (t < 64) {
        const bool act = t < RPB;
        float wv[NH3], yv[NH3];
        float ld = 0.0f;
        if (act) {
            const float* yrow = y + (size_t)(rbase + t) * NH3;
#pragma unroll
            for (int c = 0; c < NH3; ++c) {
                wv[c] = wul[t][c];
                yv[c] = yrow[c];
            }
            // factorized logsumexp over cartesian one-hot cases:
            // groups [0,2) [2,6) [6,10) [10,18)
            float m = fmaxf(wv[0], wv[1]);
            ld += m + __logf(__expf(wv[0] - m) + __expf(wv[1] - m));
            m = fmaxf(fmaxf(wv[2], wv[3]), fmaxf(wv[4], wv[5]));
            ld += m + __logf(__expf(wv[2] - m) + __expf(wv[3] - m) +
                             __expf(wv[4] - m) + __expf(wv[5] - m));
            m = fmaxf(fmaxf(wv[6], wv[7]), fmaxf(wv[8], wv[9]));
            ld += m + __logf(__expf(wv[6] - m) + __expf(wv[7] - m) +
                             __expf(wv[8] - m) + __expf(wv[9] - m));
            m = wv[10];
#pragma unroll
            for (int i = 11; i < NH3; ++i) m = fmaxf(m, wv[i]);
            float s = 0.0f;
#pragma unroll
            for (int i = 10; i < NH3; ++i) s += __expf(wv[i] - m);
            ld += m + __logf(s);
        } else {
#pragma unroll
            for (int c = 0; c < NH3; ++c) { wv[c] = 0.0f; yv[c] = 0.0f; }
        }

        // 16-lane butterflies (one wave per block; cost negligible)
        ld += __shfl_xor(ld, 1, 64);
        ld += __shfl_xor(ld, 2, 64);
        ld += __shfl_xor(ld, 4, 64);
        ld += __shfl_xor(ld, 8, 64);
#pragma unroll
        for (int c = 0; c < NH3; ++c) {
            float v = wv[c];
            v += __shfl_xor(v, 1, 64);
            v += __shfl_xor(v, 2, 64);
            v += __shfl_xor(v, 4, 64);
            v += __shfl_xor(v, 8, 64);
            wv[c] = v;
            float u = yv[c];
            u += __shfl_xor(u, 1, 64);
            u += __shfl_xor(u, 2, 64);
            u += __shfl_xor(u, 4, 64);
            u += __shfl_xor(u, 8, 64);
            yv[c] = u;
        }
        if (t == 0) {
            float* slot = ws + (size_t)blockIdx.x * WSS;
#pragma unroll
            for (int c = 0; c < NH3; ++c) {
                slot[c]       = yv[c];       // ysum partial
                slot[NH3 + c] = wv[c];       // colsum(W_user) partial
            }
            slot[36] = ld;                   // log_denom partial
        }
    }
}

__global__ __launch_bounds__(256) void finalize_loss(
    const float* __restrict__ ws, float* __restrict__ out)
{
    __shared__ double part[4][37];
    const int t = threadIdx.x;
    const int w = t >> 6, l = t & 63;
    if (l < 37) {
        double a = 0.0;
        for (int b = w * (NBLK / 4); b < (w + 1) * (NBLK / 4); ++b)
            a += (double)ws[(size_t)b * WSS + l];
        part[w][l] = a;
    }
    __syncthreads();
    if (t == 0) {
        double tot[37];
#pragma unroll
        for (int c = 0; c < 37; ++c)
            tot[c] = part[0][c] + part[1][c] + part[2][c] + part[3][c];
        double s = 0.0;
#pragma unroll
        for (int c = 0; c < NH3; ++c)
            s += tot[NH3 + c] * tot[c];             // colsum(W_user) . ysum == sum(S)
        out[(size_t)NB * NH3] = (float)(-(s - tot[36]));
    }
}

extern "C" void kernel_launch(void* const* d_in, const int* in_sizes, int n_in,
                              void* d_out, int out_size, void* d_ws, size_t ws_size,
                              hipStream_t stream) {
    const float* x  = (const float*)d_in[0];
    const float* y  = (const float*)d_in[1];
    const float* W1 = (const float*)d_in[2];
    const float* b1 = (const float*)d_in[3];
    const float* W2 = (const float*)d_in[4];
    const float* b2 = (const float*)d_in[5];
    const float* W3 = (const float*)d_in[6];
    const float* b3 = (const float*)d_in[7];
    // d_in[8] (cases) folded into the factorized logsumexp.
    float* out = (float*)d_out;
    float* ws  = (float*)d_ws;

    fused_main<<<dim3(NBLK), dim3(256), 0, stream>>>(x, y, W1, b1, W2, b2, W3, b3, out, ws);
    finalize_loss<<<dim3(1), dim3(256), 0, stream>>>(ws, out);
}